// Round 14
// baseline (1098.258 us; speedup 1.0000x reference)
//
#include <hip/hip_runtime.h>
#include <hip/hip_bf16.h>

#define M_ROWS 16384
#define D_DIM  1024
#define K_CB   4096

#define BM     256               // z rows per block
#define CTILE  256               // cb entries per chunk
#define BK     64
#define NS     8
#define COLS_PER_SPLIT (K_CB / NS)         // 512
#define NITER  16                          // 32 K-tiles, 2 per iteration
#define MBLOCKS (M_ROWS / BM)              // 64

typedef __attribute__((ext_vector_type(8))) short short8;
typedef __attribute__((ext_vector_type(16))) float f32x16;

static __device__ __forceinline__ unsigned short f2bf(float f) {
  unsigned u = __float_as_uint(f);
  unsigned r = ((u >> 16) & 1u) + 0x7FFFu;   // RNE
  return (unsigned short)((u + r) >> 16);
}

static __device__ __forceinline__ unsigned f2sortable(float f) {
  unsigned u = __float_as_uint(f);
  return (u & 0x80000000u) ? ~u : (u | 0x80000000u);
}

static __device__ __forceinline__ float sortable2f(unsigned s) {
  unsigned u = (s & 0x80000000u) ? (s ^ 0x80000000u) : ~s;
  return __uint_as_float(u);
}

static __device__ __forceinline__ void gload_lds16(const unsigned short* g, unsigned short* l) {
  __builtin_amdgcn_global_load_lds(
      (const __attribute__((address_space(1))) void*)g,
      (__attribute__((address_space(3))) void*)l, 16, 0, 0);
}

// ---------------- Kernel 1: l2-normalize rows -> bf16 ----------------
__global__ __launch_bounds__(256)
void k_normalize(const float* __restrict__ z, const float* __restrict__ cb,
                 unsigned short* __restrict__ zf, unsigned short* __restrict__ cbf) {
  const int bid = blockIdx.x;
  const float* src;
  unsigned short* dst;
  if (bid < M_ROWS) {
    src = z + (size_t)bid * D_DIM;
    dst = zf + (size_t)bid * D_DIM;
  } else {
    const int r = bid - M_ROWS;
    src = cb + (size_t)r * D_DIM;
    dst = cbf + (size_t)r * D_DIM;
  }
  const int t = threadIdx.x;
  const float4 v = ((const float4*)src)[t];
  float ss = v.x * v.x + v.y * v.y + v.z * v.z + v.w * v.w;
#pragma unroll
  for (int off = 32; off > 0; off >>= 1) ss += __shfl_down(ss, off, 64);
  __shared__ float sp[4];
  if ((t & 63) == 0) sp[t >> 6] = ss;
  __syncthreads();
  const float tot = sp[0] + sp[1] + sp[2] + sp[3];
  const float invn = 1.0f / sqrtf(tot + 1e-12f);
  ushort4 o;
  o.x = f2bf(v.x * invn);
  o.y = f2bf(v.y * invn);
  o.z = f2bf(v.z * invn);
  o.w = f2bf(v.w * invn);
  ((ushort4*)dst)[t] = o;
}

// ---------------- Kernel 2: 256x256, BK=64, 4-phase interleave (m201 port) ----------------
// 8 waves (wc in {0,1} cb x wz in {0..3} z); per wave 128cb x 64z = 4mi x 2nj
// MFMA-32 frags, kk 0..3 (K=64). Phases per iter (2 K-tiles, dbuf by parity):
//  P1: rd cf[0-1]+zr (16 b128, buf0) | stage tile 2i+1 -> buf1 | 16 MFMA | vmcnt(8)
//  P2: rd cf[2-3]                    | --                      | 16 MFMA | vmcnt(2)
//  P3: rd cf[0-1]+zr (buf1)          | stage tile 2i+2 -> buf0 | 16 MFMA | vmcnt(8)
//  P4: rd cf[2-3]                    | --                      | 16 MFMA | vmcnt(2)
// Ledger: stage = 8 loads (C rows {64-127,192-255} issued LAST; they're only
// read in P2/P4). Each chk forces exactly the loads the next phase reads,
// with >= 1 phase of cover. Buf safety: P1 stage targets buf1, whose reads
// ended at P4 barrier of prev iter; P3 targets buf0 (reads ended at P2).
// LDS 128 KB dynamic; swizzle 16B-slot s' = s ^ (row&7) (128 B rows, m201
// st_16x32); XOR-addr trick: byteoff = base ^ (kk<<5) (bits 5-6 disjoint).
__global__ __launch_bounds__(512, 2)
void k_gemm_topk8(const unsigned short* __restrict__ zf,
                  const unsigned short* __restrict__ cbf,
                  unsigned* __restrict__ part) {
  extern __shared__ __align__(16) unsigned short smem[];   // 131072 B
  // elem offsets: Z0 0 | Z1 16384 | C0 32768 | C1 49152  (each 256x64)

  const int tid  = threadIdx.x;
  const int lane = tid & 63;
  const int wid  = tid >> 6;
  const int wc   = wid & 1;
  const int wz   = wid >> 1;
  const int l31  = lane & 31;
  const int l5   = lane >> 5;

  const int wgid  = (int)blockIdx.x;
  const int split = wgid & 7;          // xcd-resident codebook slab
  const int mtile = wgid >> 3;
  const int rbase = mtile * BM;
  const int cbase = split * COLS_PER_SPLIT;

  // fragment row byte-bases within a 32 KB tile region:
  // row r, kk=0 slot a = l5 ^ (r&7); addr(kk) = base ^ (kk<<5)
  int cB[4], zB[2];
#pragma unroll
  for (int mi = 0; mi < 4; ++mi) {
    const int r = wc * 128 + mi * 32 + l31;
    cB[mi] = r * 128 + ((l5 ^ (r & 7)) << 4);
  }
#pragma unroll
  for (int nj = 0; nj < 2; ++nj) {
    const int r = wz * 64 + nj * 32 + l31;
    zB[nj] = r * 128 + ((l5 ^ (r & 7)) << 4);
  }
  const char* Zs = (const char*)smem;

  // staging: per gload, thread t covers 16B slot t of a 64-row panel:
  // row = t>>3, slot s = t&7; source pre-swizzled s ^ (row&7).
  const long stoff = (long)(tid >> 3) * D_DIM + (((tid & 7) ^ ((tid >> 3) & 7)) << 3);
  const unsigned short* zsp = zf + (size_t)rbase * D_DIM + stoff;
  const unsigned short* csp = cbf + (size_t)cbase * D_DIM + stoff;

  f32x16 acc[4][2];
#pragma unroll
  for (int mi = 0; mi < 4; ++mi)
#pragma unroll
    for (int nj = 0; nj < 2; ++nj)
#pragma unroll
      for (int r = 0; r < 16; ++r) acc[mi][nj][r] = 0.f;

  unsigned tk[2][8];                 // sorted ascending; tk[0] = min; pure u32
#pragma unroll
  for (int l = 0; l < 2; ++l)
#pragma unroll
    for (int q = 0; q < 8; ++q) tk[l][q] = 0u;

  auto STAGE_TILE = [&](int kt) {
    unsigned short* zd = smem + (kt & 1) * 16384 + tid * 8;
    unsigned short* cd = smem + 32768 + (kt & 1) * 16384 + tid * 8;
    gload_lds16(zsp,               zd);
    gload_lds16(zsp +  64 * D_DIM, zd + 4096);
    gload_lds16(zsp + 128 * D_DIM, zd + 8192);
    gload_lds16(zsp + 192 * D_DIM, zd + 12288);
    gload_lds16(csp,               cd);            // C rows 0-63   (P1/P3-read)
    gload_lds16(csp + 128 * D_DIM, cd + 8192);     // C rows 128-191(P1/P3-read)
    gload_lds16(csp +  64 * D_DIM, cd + 4096);     // C rows 64-127 (P2/P4) LAST
    gload_lds16(csp + 192 * D_DIM, cd + 12288);    // C rows 192-255(P2/P4) LAST
    if ((kt & 15) == 15) { zsp -= 960; csp += (CTILE * D_DIM - 960); }
    else                 { zsp += BK;  csp += BK; }
  };

  auto EPILOGUE = [&](int chunk) {
    const int cfb0 = cbase + chunk * CTILE + wc * 128 + l5 * 4;
#pragma unroll
    for (int nj = 0; nj < 2; ++nj) {
#pragma unroll
      for (int mi = 0; mi < 4; ++mi) {
#pragma unroll
        for (int r = 0; r < 16; ++r) {
          const float v = acc[mi][nj][r];
          const unsigned idx = (unsigned)(cfb0 + mi * 32 + (r & 3) + ((r >> 2) << 3));
          const unsigned key = (f2sortable(v) & ~0xFFFu) | idx;
          if (key > tk[nj][0]) {             // pure u32 gate (no NaN path)
            unsigned cur = key;
#pragma unroll
            for (int q = 0; q < 7; ++q) {
              const unsigned a = tk[nj][q + 1];
              tk[nj][q] = (a < cur) ? a : cur;
              cur       = (a < cur) ? cur : a;
            }
            tk[nj][7] = cur;
          }
          acc[mi][nj][r] = 0.f;
        }
      }
    }
  };

#define RD_CF(CBOFF, MIB) do { \
  _Pragma("unroll") for (int m2 = 0; m2 < 2; ++m2) \
  _Pragma("unroll") for (int kk = 0; kk < 4; ++kk) \
    cfr[m2][kk] = *(const short8*)(Zs + (CBOFF) + (cB[(MIB) + m2] ^ (kk << 5))); \
} while (0)
#define RD_Z(ZBOFF) do { \
  _Pragma("unroll") for (int nj = 0; nj < 2; ++nj) \
  _Pragma("unroll") for (int kk = 0; kk < 4; ++kk) \
    zrr[nj][kk] = *(const short8*)(Zs + (ZBOFF) + (zB[nj] ^ (kk << 5))); \
} while (0)
#define MM(MIB) do { \
  __builtin_amdgcn_s_setprio(1); \
  _Pragma("unroll") for (int kk = 0; kk < 4; ++kk) \
  _Pragma("unroll") for (int m2 = 0; m2 < 2; ++m2) \
  _Pragma("unroll") for (int nj = 0; nj < 2; ++nj) \
    acc[(MIB) + m2][nj] = __builtin_amdgcn_mfma_f32_32x32x16_bf16( \
        cfr[m2][kk], zrr[nj][kk], acc[(MIB) + m2][nj], 0, 0, 0); \
  __builtin_amdgcn_s_setprio(0); \
} while (0)
#define BAR1() do { __builtin_amdgcn_s_barrier(); \
  asm volatile("s_waitcnt lgkmcnt(0)" ::: "memory"); \
  __builtin_amdgcn_sched_barrier(0); } while (0)
#define BAR2_VM8() do { asm volatile("s_waitcnt vmcnt(8)" ::: "memory"); \
  __builtin_amdgcn_s_barrier(); __builtin_amdgcn_sched_barrier(0); } while (0)
#define BAR2_VM2() do { asm volatile("s_waitcnt vmcnt(2)" ::: "memory"); \
  __builtin_amdgcn_s_barrier(); __builtin_amdgcn_sched_barrier(0); } while (0)
#define BAR2_VM0() do { asm volatile("s_waitcnt vmcnt(0)" ::: "memory"); \
  __builtin_amdgcn_s_barrier(); __builtin_amdgcn_sched_barrier(0); } while (0)

  // prologue: stage tile 0 fully, drain, barrier
  STAGE_TILE(0);
  asm volatile("s_waitcnt vmcnt(0)" ::: "memory");
  __builtin_amdgcn_s_barrier();
  __builtin_amdgcn_sched_barrier(0);

  for (int it = 0; it < NITER; ++it) {
    short8 cfr[2][4], zrr[2][4];
    // ---- P1: tile 2it (buf0) part 1; stage tile 2it+1 -> buf1 ----
    RD_Z(0); RD_CF(65536, 0);
    STAGE_TILE(2 * it + 1);
    BAR1(); MM(0); BAR2_VM8();
    // ---- P2: tile 2it part 2 ----
    RD_CF(65536, 2);
    BAR1(); MM(2); BAR2_VM2();
    // ---- P3: tile 2it+1 (buf1) part 1; stage tile 2it+2 -> buf0 ----
    RD_Z(32768); RD_CF(98304, 0);
    if (it < NITER - 1) {
      STAGE_TILE(2 * it + 2);
      BAR1(); MM(0); BAR2_VM8();
    } else {
      BAR1(); MM(0); BAR2_VM0();
    }
    // ---- P4: tile 2it+1 part 2 ----
    RD_CF(98304, 2);
    BAR1(); MM(2);
    if (it == 7)  EPILOGUE(0);
    if (it == 15) EPILOGUE(1);
    if (it < NITER - 1) { BAR2_VM2(); } else { BAR2_VM0(); }
  }

  // merge: per z row 4 contributors (wc x l5) x 8 keys -> LDS, then top-8 scan
  __syncthreads();
  unsigned* mrg = (unsigned*)smem;     // [256][33] u32 = 33.8 KB
  {
    const int slotw = (wc * 2 + l5) * 8;
#pragma unroll
    for (int nj = 0; nj < 2; ++nj) {
      const int zrow = wz * 64 + nj * 32 + l31;
#pragma unroll
      for (int q = 0; q < 8; ++q) mrg[zrow * 33 + slotw + q] = tk[nj][q];
    }
  }
  __syncthreads();
  if (tid < BM) {
    const unsigned* c = mrg + tid * 33;
    unsigned top[8];
#pragma unroll
    for (int p = 0; p < 8; ++p) top[p] = 0u;
    unsigned tmin = 0u;
    for (int q0 = 0; q0 < 32; ++q0) {
      const unsigned k = c[(q0 + tid) & 31];   // rotate to spread banks
      if (k > tmin) {
        int ms = 0;
        unsigned mv = top[0];
#pragma unroll
        for (int q = 1; q < 8; ++q) { if (top[q] < mv) { mv = top[q]; ms = q; } }
#pragma unroll
        for (int q = 0; q < 8; ++q) top[q] = (q == ms) ? k : top[q];
        mv = top[0];
#pragma unroll
        for (int q = 1; q < 8; ++q) mv = (top[q] < mv) ? top[q] : mv;
        tmin = mv;
      }
    }
    unsigned* dst = part + ((size_t)(rbase + tid) * NS + split) * 8;
#pragma unroll
    for (int p = 0; p < 8; ++p) dst[p] = top[p];
  }
}

// ---------------- Kernel 3: merge splits, softmax, gather E, gate ----------------
template<int NSP>
__global__ __launch_bounds__(256)
void k_gate(const unsigned* __restrict__ part, const float* __restrict__ target,
            const float* __restrict__ E, float* __restrict__ out) {
  constexpr int NK = NSP * 8;
  const int row = blockIdx.x;
  const int t = threadIdx.x;
  __shared__ float s_alpha[8];
  __shared__ int s_idx[8];
  __shared__ unsigned s_key[8];

  if (t < NK) {
    unsigned k = part[(size_t)row * NK + t];
#pragma unroll
    for (int p = 0; p < 8; ++p) {
      unsigned m = k;
#pragma unroll
      for (int off = NK / 2; off > 0; off >>= 1) {
        const unsigned o = __shfl_xor(m, off, NK);
        m = (m > o) ? m : o;
      }
      if (k == m) { s_key[p] = k; k = 0u; }  // keys distinct (idx in low bits)
    }
  }
  __syncthreads();
  if (t < 8) {
    const unsigned key = s_key[t];
    const float val  = 10.0f * sortable2f(key & ~0xFFFu);
    const float vmax = 10.0f * sortable2f(s_key[0] & ~0xFFFu);
    const float e = expf(val - vmax);
    float s = e;
#pragma unroll
    for (int off = 4; off > 0; off >>= 1) s += __shfl_xor(s, off, 8);
    s_alpha[t] = e / s;
    s_idx[t] = (int)(key & 0xFFFu);
  }
  __syncthreads();

  float4 g = {0.f, 0.f, 0.f, 0.f};
#pragma unroll
  for (int p = 0; p < 8; ++p) {
    const float a = s_alpha[p];
    const float4 e4 = ((const float4*)E)[(size_t)s_idx[p] * 256 + t];
    g.x += a * e4.x;
    g.y += a * e4.y;
    g.z += a * e4.z;
    g.w += a * e4.w;
  }
  const float4 tg = ((const float4*)target)[(size_t)row * 256 + t];
  float4 o;
  o.x = tg.x * (1.f + g.x);
  o.y = tg.y * (1.f + g.y);
  o.z = tg.z * (1.f + g.z);
  o.w = tg.w * (1.f + g.w);
  ((float4*)out)[(size_t)row * 256 + t] = o;
}

extern "C" void kernel_launch(void* const* d_in, const int* in_sizes, int n_in,
                              void* d_out, int out_size, void* d_ws, size_t ws_size,
                              hipStream_t stream) {
  const float* z      = (const float*)d_in[0];
  const float* target = (const float*)d_in[1];
  const float* cb     = (const float*)d_in[2];
  const float* E      = (const float*)d_in[3];
  float* out = (float*)d_out;

  // d_out doubles as scratch for the bf16 normalized matrices (dead before k_gate writes)
  unsigned short* zf  = (unsigned short*)d_out;                       // 32 MB
  unsigned short* cbf = (unsigned short*)((char*)d_out + 33554432);   // 8 MB @ +32MB
  unsigned* part = (unsigned*)d_ws;                                   // 4 MB

  hipFuncSetAttribute((const void*)k_gemm_topk8,
                      hipFuncAttributeMaxDynamicSharedMemorySize, 131072);

  k_normalize<<<dim3(M_ROWS + K_CB), dim3(256), 0, stream>>>(z, cb, zf, cbf);
  k_gemm_topk8<<<dim3(MBLOCKS * NS), dim3(512), 131072, stream>>>(zf, cbf, part);
  k_gate<NS><<<dim3(M_ROWS), dim3(256), 0, stream>>>(part, target, E, out);
}

// Round 15
// 227.304 us; speedup vs baseline: 4.8317x; 4.8317x over previous
//
#include <hip/hip_runtime.h>
#include <hip/hip_bf16.h>

#define M_ROWS 16384
#define D_DIM  1024
#define K_CB   4096

#define ZTILE  128               // z rows per block
#define CTILE  256               // cb entries per chunk
#define NS     8
#define COLS_PER_SPLIT (K_CB / NS)   // 512
#define BODIES 32                    // 2 chunks x 16 (K=1024 / 64 per body)
#define MBLOCKS (M_ROWS / ZTILE)     // 128

typedef __attribute__((ext_vector_type(2))) long long2v;
typedef __attribute__((ext_vector_type(16))) float f32x16;

static __device__ __forceinline__ unsigned f2sortable(float f) {
  unsigned u = __float_as_uint(f);
  return (u & 0x80000000u) ? ~u : (u | 0x80000000u);
}

static __device__ __forceinline__ float sortable2f(unsigned s) {
  unsigned u = (s & 0x80000000u) ? (s ^ 0x80000000u) : ~s;
  return __uint_as_float(u);
}

// OCP e4m3fn encode, RNE, satfinite.
static __device__ __forceinline__ unsigned char f2e4m3(float f) {
  float a = fabsf(f);
  const unsigned s = (__float_as_uint(f) >> 24) & 0x80u;
  if (a < 0.015625f) {                       // subnormal range (< 2^-6)
    int m = (int)(a * 512.0f + 0.5f);        // round(a / 2^-9)
    if (m >= 8) return (unsigned char)(s | 0x08u);   // -> 2^-6 normal
    return (unsigned char)(s | (unsigned)m);
  }
  if (a > 448.0f) a = 448.0f;
  unsigned t = __float_as_uint(a);
  t += 0x7FFFFu + ((t >> 20) & 1u);          // RNE to 3 mantissa bits
  int e = (int)(t >> 23) - 127;
  unsigned m = (t >> 20) & 7u;
  if (e > 8 || (e == 8 && m == 7u)) { e = 8; m = 6u; }   // clamp to 448
  return (unsigned char)(s | ((unsigned)(e + 7) << 3) | m);
}

static __device__ __forceinline__ void gload_lds16(const unsigned char* g, unsigned char* l) {
  __builtin_amdgcn_global_load_lds(
      (const __attribute__((address_space(1))) void*)g,
      (__attribute__((address_space(3))) void*)l, 16, 0, 0);
}

// ---------------- Kernel 1: l2-normalize rows -> fp8 e4m3 (x16, k-permuted) ----------------
// Output scaled by 16 (e4m3 sweet range); BOTH operands scaled+permuted the
// same way -> dot x256, top-k order preserved; k3 rescales alpha inputs.
// k-permutation: swap bits 3,4 of k within each 32-group, so that each 16B
// LDS slot = the MFMA (kk-pair, l5) fragment pair (pure b128 fragment reads).
__global__ __launch_bounds__(256)
void k_normalize(const float* __restrict__ z, const float* __restrict__ cb,
                 unsigned char* __restrict__ zf8, unsigned char* __restrict__ cbf8) {
  const int bid = blockIdx.x;
  const float* src;
  unsigned char* dst;
  if (bid < M_ROWS) {
    src = z + (size_t)bid * D_DIM;
    dst = zf8 + (size_t)bid * D_DIM;
  } else {
    const int r = bid - M_ROWS;
    src = cb + (size_t)r * D_DIM;
    dst = cbf8 + (size_t)r * D_DIM;
  }
  const int t = threadIdx.x;
  const float4 v = ((const float4*)src)[t];
  float ss = v.x * v.x + v.y * v.y + v.z * v.z + v.w * v.w;
#pragma unroll
  for (int off = 32; off > 0; off >>= 1) ss += __shfl_down(ss, off, 64);
  __shared__ float sp[4];
  if ((t & 63) == 0) sp[t >> 6] = ss;
  __syncthreads();
  const float tot = sp[0] + sp[1] + sp[2] + sp[3];
  const float sc = 16.0f / sqrtf(tot + 1e-12f);     // l2norm * 16
  uchar4 o;
  o.x = f2e4m3(v.x * sc);
  o.y = f2e4m3(v.y * sc);
  o.z = f2e4m3(v.z * sc);
  o.w = f2e4m3(v.w * sc);
  const int d = 4 * t;   // bits 3,4 of d constant over the 4 lanes' elems
  const int pd = (d & ~24) | (((d >> 3) & 1) << 4) | (((d >> 4) & 1) << 3);
  *(uchar4*)(dst + pd) = o;
}

// ---------------- Kernel 2: z128 x cb256 tile, fp8 32x32x16 MFMA, BK=64 ----------------
// 4 waves (wc in {0,1} cb x wz in {0,1} z); per wave 128cb x 64z = 4mi x 2nj,
// 32 MFMA/body (2x the bf16 MFMA wall per barrier; LDS bytes/FLOP halved).
// 48 KB LDS dbuf; acc 128 + ~70 regs -> launch_bounds(256,2) = 2 blocks/CU
// (cross-block drift hides latency; R14's spill came from a 128-reg cap).
// Rows 64 B; swizzle 16B-slot s' = s ^ ((r>>1)&3) (R12-proven geometry).
// Fragment slot (kkp,l5) holds k = {32kkp+8*l5+[0..8), 32kkp+16+8*l5+[0..8)}
// via k1's bit-3/4 swap -> .x/.y of a b128 feed MFMA kk=2kkp, 2kkp+1.
__global__ __launch_bounds__(256, 2)
void k_gemm_topk(const unsigned char* __restrict__ zf8,
                 const unsigned char* __restrict__ cbf8,
                 unsigned* __restrict__ part) {
  __shared__ __align__(16) unsigned char smem[49152];  // Z0|Z1 8KB each, C0|C1 16KB each

  const int tid  = threadIdx.x;
  const int lane = tid & 63;
  const int wid  = tid >> 6;
  const int wc   = wid & 1;    // cb 128-block
  const int wz   = wid >> 1;   // z 64-block
  const int l31  = lane & 31;
  const int l5   = lane >> 5;

  const int wgid  = (int)blockIdx.x;
  const int split = wgid & 7;          // xcd-resident codebook slab
  const int mtile = wgid >> 3;
  const int rbase = mtile * ZTILE;
  const int cbase = split * COLS_PER_SPLIT;

  // fragment byte bases (kkp=0): addr(kkp) = base ^ (kkp<<5)
  int cA[4], zA[2];
#pragma unroll
  for (int mi = 0; mi < 4; ++mi) {
    const int r = wc * 128 + mi * 32 + l31;
    cA[mi] = r * 64 + ((l5 ^ ((r >> 1) & 3)) << 4);
  }
#pragma unroll
  for (int nj = 0; nj < 2; ++nj) {
    const int r = wz * 64 + nj * 32 + l31;
    zA[nj] = r * 64 + ((l5 ^ ((r >> 1) & 3)) << 4);
  }

  // staging: thread -> row t>>2, 16B slot t&3; source pre-swizzled.
  const long stoff = (long)(tid >> 2) * D_DIM + (((tid & 3) ^ ((tid >> 3) & 3)) << 4);
  const unsigned char* zsp = zf8 + (size_t)rbase * D_DIM + stoff;
  const unsigned char* csp = cbf8 + (size_t)cbase * D_DIM + stoff;

  f32x16 acc[4][2];
#pragma unroll
  for (int mi = 0; mi < 4; ++mi)
#pragma unroll
    for (int nj = 0; nj < 2; ++nj)
#pragma unroll
      for (int r = 0; r < 16; ++r) acc[mi][nj][r] = 0.f;

  unsigned tk[2][8];                 // sorted ascending; tk[0] = min; pure u32
#pragma unroll
  for (int l = 0; l < 2; ++l)
#pragma unroll
    for (int q = 0; q < 8; ++q) tk[l][q] = 0u;

  auto STAGE = [&](int par) {
    unsigned char* zd = smem + par * 8192 + tid * 16;
    unsigned char* cd = smem + 16384 + par * 16384 + tid * 16;
    gload_lds16(zsp,                zd);
    gload_lds16(zsp +  64 * D_DIM,  zd + 4096);
    gload_lds16(csp,                cd);
    gload_lds16(csp +  64 * D_DIM,  cd + 4096);
    gload_lds16(csp + 128 * D_DIM,  cd + 8192);
    gload_lds16(csp + 192 * D_DIM,  cd + 12288);
  };
  auto ADV = [&](int stagedBody) {
    if (((stagedBody + 1) & 15) == 0) {
      zsp += 64 - D_DIM;                       // Z k-tiles repeat each chunk
      csp += 64 + (CTILE * D_DIM - D_DIM);     // C -> next 256-entry slab
    } else {
      zsp += 64; csp += 64;
    }
  };
  auto COMPUTE = [&](int par) {
    const unsigned char* Z = smem + par * 8192;
    const unsigned char* C = smem + 16384 + par * 16384;
#pragma unroll
    for (int kkp = 0; kkp < 2; ++kkp) {
      long2v cf[4], zr[2];
#pragma unroll
      for (int mi = 0; mi < 4; ++mi) cf[mi] = *(const long2v*)(C + (cA[mi] ^ (kkp << 5)));
#pragma unroll
      for (int nj = 0; nj < 2; ++nj) zr[nj] = *(const long2v*)(Z + (zA[nj] ^ (kkp << 5)));
#pragma unroll
      for (int mi = 0; mi < 4; ++mi)
#pragma unroll
        for (int nj = 0; nj < 2; ++nj) {
          acc[mi][nj] = __builtin_amdgcn_mfma_f32_32x32x16_fp8_fp8(
              cf[mi].x, zr[nj].x, acc[mi][nj], 0, 0, 0);
          acc[mi][nj] = __builtin_amdgcn_mfma_f32_32x32x16_fp8_fp8(
              cf[mi].y, zr[nj].y, acc[mi][nj], 0, 0, 0);
        }
    }
  };
  auto EPILOGUE = [&](int chunk) {
    const int cfb0 = cbase + chunk * CTILE + wc * 128 + l5 * 4;
#pragma unroll
    for (int nj = 0; nj < 2; ++nj) {
#pragma unroll
      for (int mi = 0; mi < 4; ++mi) {
#pragma unroll
        for (int r = 0; r < 16; ++r) {
          const float v = acc[mi][nj][r];
          const unsigned idx = (unsigned)(cfb0 + mi * 32 + (r & 3) + ((r >> 2) << 3));
          const unsigned key = (f2sortable(v) & ~0xFFFu) | idx;
          if (key > tk[nj][0]) {               // pure u32 gate; sorted insert
            unsigned cur = key;
#pragma unroll
            for (int q = 0; q < 7; ++q) {
              const unsigned a = tk[nj][q + 1];
              tk[nj][q] = (a < cur) ? a : cur;
              cur       = (a < cur) ? cur : a;
            }
            tk[nj][7] = cur;
          }
          acc[mi][nj][r] = 0.f;
        }
      }
    }
  };

  // prologue: stage body 0 -> buf0
  STAGE(0);
  ADV(0);
  __syncthreads();

  for (int b = 0; b < BODIES; b += 2) {
    STAGE(1);              // body b+1 -> buf1
    ADV(b + 1);
    COMPUTE(0);
    __syncthreads();

    if (b + 2 < BODIES) {
      STAGE(0);            // body b+2 -> buf0
      ADV(b + 2);
    }
    COMPUTE(1);
    if ((b & 15) == 14) EPILOGUE((b + 1) >> 4);   // chunks end at bodies 15/31
    __syncthreads();
  }

  // merge: per z row 4 contributors (wc x l5) x 8 keys -> LDS, then top-8 scan
  unsigned* mrg = (unsigned*)smem;     // [128][33] u32 = 16.9 KB
  {
    const int slotw = (wc * 2 + l5) * 8;
#pragma unroll
    for (int nj = 0; nj < 2; ++nj) {
      const int zrow = wz * 64 + nj * 32 + l31;
#pragma unroll
      for (int q = 0; q < 8; ++q) mrg[zrow * 33 + slotw + q] = tk[nj][q];
    }
  }
  __syncthreads();
  if (tid < ZTILE) {
    const unsigned* c = mrg + tid * 33;
    unsigned top[8];
#pragma unroll
    for (int p = 0; p < 8; ++p) top[p] = 0u;
    unsigned tmin = 0u;
    for (int q0 = 0; q0 < 32; ++q0) {
      const unsigned k = c[(q0 + tid) & 31];   // rotate to spread banks
      if (k > tmin) {
        int ms = 0;
        unsigned mv = top[0];
#pragma unroll
        for (int q = 1; q < 8; ++q) { if (top[q] < mv) { mv = top[q]; ms = q; } }
#pragma unroll
        for (int q = 0; q < 8; ++q) top[q] = (q == ms) ? k : top[q];
        mv = top[0];
#pragma unroll
        for (int q = 1; q < 8; ++q) mv = (top[q] < mv) ? top[q] : mv;
        tmin = mv;
      }
    }
    unsigned* dst = part + ((size_t)(rbase + tid) * NS + split) * 8;
#pragma unroll
    for (int p = 0; p < 8; ++p) dst[p] = top[p];
  }
}

// ---------------- Kernel 3: merge splits, softmax, gather E, gate ----------------
// NOTE: logits were computed on x16-scaled operands -> raw dot = 256x; the
// softmax input is TAU * dot / 256.
template<int NSP>
__global__ __launch_bounds__(256)
void k_gate(const unsigned* __restrict__ part, const float* __restrict__ target,
            const float* __restrict__ E, float* __restrict__ out) {
  constexpr int NK = NSP * 8;
  const int row = blockIdx.x;
  const int t = threadIdx.x;
  __shared__ float s_alpha[8];
  __shared__ int s_idx[8];
  __shared__ unsigned s_key[8];

  if (t < NK) {
    unsigned k = part[(size_t)row * NK + t];
#pragma unroll
    for (int p = 0; p < 8; ++p) {
      unsigned m = k;
#pragma unroll
      for (int off = NK / 2; off > 0; off >>= 1) {
        const unsigned o = __shfl_xor(m, off, NK);
        m = (m > o) ? m : o;
      }
      if (k == m) { s_key[p] = k; k = 0u; }  // keys distinct (idx in low bits)
    }
  }
  __syncthreads();
  if (t < 8) {
    const float SCALE = 10.0f / 256.0f;
    const unsigned key = s_key[t];
    const float val  = SCALE * sortable2f(key & ~0xFFFu);
    const float vmax = SCALE * sortable2f(s_key[0] & ~0xFFFu);
    const float e = expf(val - vmax);
    float s = e;
#pragma unroll
    for (int off = 4; off > 0; off >>= 1) s += __shfl_xor(s, off, 8);
    s_alpha[t] = e / s;
    s_idx[t] = (int)(key & 0xFFFu);
  }
  __syncthreads();

  float4 g = {0.f, 0.f, 0.f, 0.f};
#pragma unroll
  for (int p = 0; p < 8; ++p) {
    const float a = s_alpha[p];
    const float4 e4 = ((const float4*)E)[(size_t)s_idx[p] * 256 + t];
    g.x += a * e4.x;
    g.y += a * e4.y;
    g.z += a * e4.z;
    g.w += a * e4.w;
  }
  const float4 tg = ((const float4*)target)[(size_t)row * 256 + t];
  float4 o;
  o.x = tg.x * (1.f + g.x);
  o.y = tg.y * (1.f + g.y);
  o.z = tg.z * (1.f + g.z);
  o.w = tg.w * (1.f + g.w);
  ((float4*)out)[(size_t)row * 256 + t] = o;
}

extern "C" void kernel_launch(void* const* d_in, const int* in_sizes, int n_in,
                              void* d_out, int out_size, void* d_ws, size_t ws_size,
                              hipStream_t stream) {
  const float* z      = (const float*)d_in[0];
  const float* target = (const float*)d_in[1];
  const float* cb     = (const float*)d_in[2];
  const float* E      = (const float*)d_in[3];
  float* out = (float*)d_out;

  // d_out doubles as scratch for the fp8 normalized matrices (dead before k_gate writes)
  unsigned char* zf8  = (unsigned char*)d_out;                        // 16 MB
  unsigned char* cbf8 = (unsigned char*)d_out + 16777216;             // 4 MB @ +16MB
  unsigned* part = (unsigned*)d_ws;                                   // 4 MB

  k_normalize<<<dim3(M_ROWS + K_CB), dim3(256), 0, stream>>>(z, cb, zf8, cbf8);
  k_gemm_topk<<<dim3(MBLOCKS * NS), dim3(256), 0, stream>>>(zf8, cbf8, part);
  k_gate<NS><<<dim3(M_ROWS), dim3(256), 0, stream>>>(part, target, E, out);
}

// Round 16
// 210.196 us; speedup vs baseline: 5.2249x; 1.0814x over previous
//
#include <hip/hip_runtime.h>
#include <hip/hip_bf16.h>

#define M_ROWS 16384
#define D_DIM  1024
#define K_CB   4096

#define ZTILE  128               // z rows per block
#define CTILE  256               // cb entries per chunk
#define NS     8
#define COLS_PER_SPLIT (K_CB / NS)   // 512
#define BODIES 32                    // 2 chunks x 16 (K=1024 / 64 per body)
#define MBLOCKS (M_ROWS / ZTILE)     // 128

typedef __attribute__((ext_vector_type(4))) int  int4v;
typedef __attribute__((ext_vector_type(8))) int  int8v;
typedef __attribute__((ext_vector_type(16))) float f32x16;

static __device__ __forceinline__ unsigned f2sortable(float f) {
  unsigned u = __float_as_uint(f);
  return (u & 0x80000000u) ? ~u : (u | 0x80000000u);
}

static __device__ __forceinline__ float sortable2f(unsigned s) {
  unsigned u = (s & 0x80000000u) ? (s ^ 0x80000000u) : ~s;
  return __uint_as_float(u);
}

// OCP e4m3fn encode, RNE, satfinite.
static __device__ __forceinline__ unsigned char f2e4m3(float f) {
  float a = fabsf(f);
  const unsigned s = (__float_as_uint(f) >> 24) & 0x80u;
  if (a < 0.015625f) {                       // subnormal range (< 2^-6)
    int m = (int)(a * 512.0f + 0.5f);        // round(a / 2^-9)
    if (m >= 8) return (unsigned char)(s | 0x08u);   // -> 2^-6 normal
    return (unsigned char)(s | (unsigned)m);
  }
  if (a > 448.0f) a = 448.0f;
  unsigned t = __float_as_uint(a);
  t += 0x7FFFFu + ((t >> 20) & 1u);          // RNE to 3 mantissa bits
  int e = (int)(t >> 23) - 127;
  unsigned m = (t >> 20) & 7u;
  if (e > 8 || (e == 8 && m == 7u)) { e = 8; m = 6u; }   // clamp to 448
  return (unsigned char)(s | ((unsigned)(e + 7) << 3) | m);
}

static __device__ __forceinline__ void gload_lds16(const unsigned char* g, unsigned char* l) {
  __builtin_amdgcn_global_load_lds(
      (const __attribute__((address_space(1))) void*)g,
      (__attribute__((address_space(3))) void*)l, 16, 0, 0);
}

// ---------------- Kernel 1: l2-normalize rows -> fp8 e4m3 (x16, linear k) ----------------
// Output scaled by 16 (e4m3 sweet range); both operands scaled the same way
// -> dot x256, top-k order preserved; k3 rescales (SCALE = 10/256).
// (R15's bit-3/4 k-permutation removed: the scaled 32x32x64 MFMA wants
// k-linear 32B per lane, which the slot-XOR LDS layout already delivers.)
__global__ __launch_bounds__(256)
void k_normalize(const float* __restrict__ z, const float* __restrict__ cb,
                 unsigned char* __restrict__ zf8, unsigned char* __restrict__ cbf8) {
  const int bid = blockIdx.x;
  const float* src;
  unsigned char* dst;
  if (bid < M_ROWS) {
    src = z + (size_t)bid * D_DIM;
    dst = zf8 + (size_t)bid * D_DIM;
  } else {
    const int r = bid - M_ROWS;
    src = cb + (size_t)r * D_DIM;
    dst = cbf8 + (size_t)r * D_DIM;
  }
  const int t = threadIdx.x;
  const float4 v = ((const float4*)src)[t];
  float ss = v.x * v.x + v.y * v.y + v.z * v.z + v.w * v.w;
#pragma unroll
  for (int off = 32; off > 0; off >>= 1) ss += __shfl_down(ss, off, 64);
  __shared__ float sp[4];
  if ((t & 63) == 0) sp[t >> 6] = ss;
  __syncthreads();
  const float tot = sp[0] + sp[1] + sp[2] + sp[3];
  const float sc = 16.0f / sqrtf(tot + 1e-12f);     // l2norm * 16
  uchar4 o;
  o.x = f2e4m3(v.x * sc);
  o.y = f2e4m3(v.y * sc);
  o.z = f2e4m3(v.z * sc);
  o.w = f2e4m3(v.w * sc);
  *(uchar4*)(dst + 4 * t) = o;
}

// ---------------- Kernel 2: z128 x cb256 tile, MX-scaled fp8 32x32x64, BK=64 ----------------
// 4 waves (wc in {0,1} cb x wz in {0,1} z); per wave 128cb x 64z = 4mi x 2nj,
// 8 scaled MFMA/body (K=64 each, scales = E8M0 127 = 1.0 -> exact fp8 GEMM
// at 2.1x the non-scaled rate, 1/4 the instruction count of R15).
// Fragment: lane row = l&31, k = 32*(l>>5)+[0..32) = 32 linear bytes (v8i32)
// = two b128 at r*64 + 16*((2*l5)^rho(r)) and that addr ^16, where LDS slot
// sigma holds global slot sigma^rho(r), rho = (r>>1)&3 (R12/R15-proven
// staging swizzle). Bank audit: 8 lanes/quad per b128 = floor, same as R15.
__global__ __launch_bounds__(256, 2)
void k_gemm_topk(const unsigned char* __restrict__ zf8,
                 const unsigned char* __restrict__ cbf8,
                 unsigned* __restrict__ part) {
  __shared__ __align__(16) unsigned char smem[49152];  // Z0|Z1 8KB each, C0|C1 16KB each

  const int tid  = threadIdx.x;
  const int lane = tid & 63;
  const int wid  = tid >> 6;
  const int wc   = wid & 1;    // cb 128-block
  const int wz   = wid >> 1;   // z 64-block
  const int l31  = lane & 31;
  const int l5   = lane >> 5;

  const int wgid  = (int)blockIdx.x;
  const int split = wgid & 7;          // xcd-resident codebook slab
  const int mtile = wgid >> 3;
  const int rbase = mtile * ZTILE;
  const int cbase = split * COLS_PER_SPLIT;

  // fragment byte bases: sigma0 = (2*l5) ^ rho(r); second b128 at base ^ 16
  int cA[4], zA[2];
#pragma unroll
  for (int mi = 0; mi < 4; ++mi) {
    const int r = wc * 128 + mi * 32 + l31;
    cA[mi] = r * 64 + (((2 * l5) ^ ((r >> 1) & 3)) << 4);
  }
#pragma unroll
  for (int nj = 0; nj < 2; ++nj) {
    const int r = wz * 64 + nj * 32 + l31;
    zA[nj] = r * 64 + (((2 * l5) ^ ((r >> 1) & 3)) << 4);
  }

  // staging: thread -> row t>>2, 16B slot t&3; source pre-swizzled (slot ^ rho(row)).
  const long stoff = (long)(tid >> 2) * D_DIM + (((tid & 3) ^ ((tid >> 3) & 3)) << 4);
  const unsigned char* zsp = zf8 + (size_t)rbase * D_DIM + stoff;
  const unsigned char* csp = cbf8 + (size_t)cbase * D_DIM + stoff;

  f32x16 acc[4][2];
#pragma unroll
  for (int mi = 0; mi < 4; ++mi)
#pragma unroll
    for (int nj = 0; nj < 2; ++nj)
#pragma unroll
      for (int r = 0; r < 16; ++r) acc[mi][nj][r] = 0.f;

  unsigned tk[2][8];                 // sorted ascending; tk[0] = min; pure u32
#pragma unroll
  for (int l = 0; l < 2; ++l)
#pragma unroll
    for (int q = 0; q < 8; ++q) tk[l][q] = 0u;

  auto STAGE = [&](int par) {
    unsigned char* zd = smem + par * 8192 + tid * 16;
    unsigned char* cd = smem + 16384 + par * 16384 + tid * 16;
    gload_lds16(zsp,                zd);
    gload_lds16(zsp +  64 * D_DIM,  zd + 4096);
    gload_lds16(csp,                cd);
    gload_lds16(csp +  64 * D_DIM,  cd + 4096);
    gload_lds16(csp + 128 * D_DIM,  cd + 8192);
    gload_lds16(csp + 192 * D_DIM,  cd + 12288);
  };
  auto ADV = [&](int stagedBody) {
    if (((stagedBody + 1) & 15) == 0) {
      zsp += 64 - D_DIM;                       // Z k-tiles repeat each chunk
      csp += 64 + (CTILE * D_DIM - D_DIM);     // C -> next 256-entry slab
    } else {
      zsp += 64; csp += 64;
    }
  };
  auto COMPUTE = [&](int par) {
    const unsigned char* Z = smem + par * 8192;
    const unsigned char* C = smem + 16384 + par * 16384;
    int8v cf[4], zr[2];
#pragma unroll
    for (int mi = 0; mi < 4; ++mi) {
      const int4v lo = *(const int4v*)(C + cA[mi]);
      const int4v hi = *(const int4v*)(C + (cA[mi] ^ 16));
      cf[mi] = __builtin_shufflevector(lo, hi, 0, 1, 2, 3, 4, 5, 6, 7);
    }
#pragma unroll
    for (int nj = 0; nj < 2; ++nj) {
      const int4v lo = *(const int4v*)(Z + zA[nj]);
      const int4v hi = *(const int4v*)(Z + (zA[nj] ^ 16));
      zr[nj] = __builtin_shufflevector(lo, hi, 0, 1, 2, 3, 4, 5, 6, 7);
    }
#pragma unroll
    for (int mi = 0; mi < 4; ++mi)
#pragma unroll
      for (int nj = 0; nj < 2; ++nj)
        acc[mi][nj] = __builtin_amdgcn_mfma_scale_f32_32x32x64_f8f6f4(
            cf[mi], zr[nj], acc[mi][nj],
            0 /*cbsz: A=fp8 e4m3*/, 0 /*blgp: B=fp8 e4m3*/,
            0, 0x7F /*scale A = 2^0*/, 0, 0x7F /*scale B = 2^0*/);
  };
  auto EPILOGUE = [&](int chunk) {
    const int cfb0 = cbase + chunk * CTILE + wc * 128 + l5 * 4;
#pragma unroll
    for (int nj = 0; nj < 2; ++nj) {
#pragma unroll
      for (int mi = 0; mi < 4; ++mi) {
#pragma unroll
        for (int r = 0; r < 16; ++r) {
          const float v = acc[mi][nj][r];
          const unsigned idx = (unsigned)(cfb0 + mi * 32 + (r & 3) + ((r >> 2) << 3));
          const unsigned key = (f2sortable(v) & ~0xFFFu) | idx;
          if (key > tk[nj][0]) {               // pure u32 gate; sorted insert
            unsigned cur = key;
#pragma unroll
            for (int q = 0; q < 7; ++q) {
              const unsigned a = tk[nj][q + 1];
              tk[nj][q] = (a < cur) ? a : cur;
              cur       = (a < cur) ? cur : a;
            }
            tk[nj][7] = cur;
          }
          acc[mi][nj][r] = 0.f;
        }
      }
    }
  };

  // prologue: stage body 0 -> buf0
  STAGE(0);
  ADV(0);
  __syncthreads();

  for (int b = 0; b < BODIES; b += 2) {
    STAGE(1);              // body b+1 -> buf1
    ADV(b + 1);
    COMPUTE(0);
    __syncthreads();

    if (b + 2 < BODIES) {
      STAGE(0);            // body b+2 -> buf0
      ADV(b + 2);
    }
    COMPUTE(1);
    if ((b & 15) == 14) EPILOGUE((b + 1) >> 4);   // chunks end at bodies 15/31
    __syncthreads();
  }

  // merge: per z row 4 contributors (wc x l5) x 8 keys -> LDS, then top-8 scan
  unsigned* mrg = (unsigned*)smem;     // [128][33] u32 = 16.9 KB
  {
    const int slotw = (wc * 2 + l5) * 8;
#pragma unroll
    for (int nj = 0; nj < 2; ++nj) {
      const int zrow = wz * 64 + nj * 32 + l31;
#pragma unroll
      for (int q = 0; q < 8; ++q) mrg[zrow * 33 + slotw + q] = tk[nj][q];
    }
  }
  __syncthreads();
  if (tid < ZTILE) {
    const unsigned* c = mrg + tid * 33;
    unsigned top[8];
#pragma unroll
    for (int p = 0; p < 8; ++p) top[p] = 0u;
    unsigned tmin = 0u;
    for (int q0 = 0; q0 < 32; ++q0) {
      const unsigned k = c[(q0 + tid) & 31];   // rotate to spread banks
      if (k > tmin) {
        int ms = 0;
        unsigned mv = top[0];
#pragma unroll
        for (int q = 1; q < 8; ++q) { if (top[q] < mv) { mv = top[q]; ms = q; } }
#pragma unroll
        for (int q = 0; q < 8; ++q) top[q] = (q == ms) ? k : top[q];
        mv = top[0];
#pragma unroll
        for (int q = 1; q < 8; ++q) mv = (top[q] < mv) ? top[q] : mv;
        tmin = mv;
      }
    }
    unsigned* dst = part + ((size_t)(rbase + tid) * NS + split) * 8;
#pragma unroll
    for (int p = 0; p < 8; ++p) dst[p] = top[p];
  }
}

// ---------------- Kernel 3: merge splits, softmax, gather E, gate ----------------
// logits computed on x16-scaled operands -> raw dot = 256x; softmax input is
// TAU * dot / 256.
template<int NSP>
__global__ __launch_bounds__(256)
void k_gate(const unsigned* __restrict__ part, const float* __restrict__ target,
            const float* __restrict__ E, float* __restrict__ out) {
  constexpr int NK = NSP * 8;
  const int row = blockIdx.x;
  const int t = threadIdx.x;
  __shared__ float s_alpha[8];
  __shared__ int s_idx[8];
  __shared__ unsigned s_key[8];

  if (t < NK) {
    unsigned k = part[(size_t)row * NK + t];
#pragma unroll
    for (int p = 0; p < 8; ++p) {
      unsigned m = k;
#pragma unroll
      for (int off = NK / 2; off > 0; off >>= 1) {
        const unsigned o = __shfl_xor(m, off, NK);
        m = (m > o) ? m : o;
      }
      if (k == m) { s_key[p] = k; k = 0u; }  // keys distinct (idx in low bits)
    }
  }
  __syncthreads();
  if (t < 8) {
    const float SCALE = 10.0f / 256.0f;
    const unsigned key = s_key[t];
    const float val  = SCALE * sortable2f(key & ~0xFFFu);
    const float vmax = SCALE * sortable2f(s_key[0] & ~0xFFFu);
    const float e = expf(val - vmax);
    float s = e;
#pragma unroll
    for (int off = 4; off > 0; off >>= 1) s += __shfl_xor(s, off, 8);
    s_alpha[t] = e / s;
    s_idx[t] = (int)(key & 0xFFFu);
  }
  __syncthreads();

  float4 g = {0.f, 0.f, 0.f, 0.f};
#pragma unroll
  for (int p = 0; p < 8; ++p) {
    const float a = s_alpha[p];
    const float4 e4 = ((const float4*)E)[(size_t)s_idx[p] * 256 + t];
    g.x += a * e4.x;
    g.y += a * e4.y;
    g.z += a * e4.z;
    g.w += a * e4.w;
  }
  const float4 tg = ((const float4*)target)[(size_t)row * 256 + t];
  float4 o;
  o.x = tg.x * (1.f + g.x);
  o.y = tg.y * (1.f + g.y);
  o.z = tg.z * (1.f + g.z);
  o.w = tg.w * (1.f + g.w);
  ((float4*)out)[(size_t)row * 256 + t] = o;
}

extern "C" void kernel_launch(void* const* d_in, const int* in_sizes, int n_in,
                              void* d_out, int out_size, void* d_ws, size_t ws_size,
                              hipStream_t stream) {
  const float* z      = (const float*)d_in[0];
  const float* target = (const float*)d_in[1];
  const float* cb     = (const float*)d_in[2];
  const float* E      = (const float*)d_in[3];
  float* out = (float*)d_out;

  // d_out doubles as scratch for the fp8 normalized matrices (dead before k_gate writes)
  unsigned char* zf8  = (unsigned char*)d_out;                        // 16 MB
  unsigned char* cbf8 = (unsigned char*)d_out + 16777216;             // 4 MB @ +16MB
  unsigned* part = (unsigned*)d_ws;                                   // 4 MB

  k_normalize<<<dim3(M_ROWS + K_CB), dim3(256), 0, stream>>>(z, cb, zf8, cbf8);
  k_gemm_topk<<<dim3(MBLOCKS * NS), dim3(256), 0, stream>>>(zf8, cbf8, part);
  k_gate<NS><<<dim3(M_ROWS), dim3(256), 0, stream>>>(part, target, E, out);
}